// Round 6
// baseline (747.347 us; speedup 1.0000x reference)
//
#include <hip/hip_runtime.h>
#include <hip/hip_bf16.h>

// PhysicsGraphFusion: B=1024, N=7, D=1024
// Outputs (flat): fused (B*D), updated (B*N*D), imp (B*N), attn (B*N*N), phys (1), align (1)
//
// All bf16 matrices use "fragment-tile packed" layout: element (r,k) of a
// matrix with KB = cols/32 k-blocks lives at
//   ((r>>4)*KB + (k>>5))*512 + ((k>>3)&3)*128 + (r&15)*8 + (k&7)
// so a wave's 64 x 16B DMA chunks for one (16-row group, 32-k block) are
// contiguous in HBM (coalesced) AND lane-linear in LDS (conflict-free reads).

typedef __attribute__((ext_vector_type(8))) short bf16x8;
typedef __attribute__((ext_vector_type(4))) float f32x4;

#define PIDX(r, kk, KB) \
    ((((size_t)(((r) >> 4) * (KB) + ((kk) >> 5))) << 9) + \
     ((((((kk) >> 3) & 3) << 4) + ((r) & 15)) << 3) + ((kk) & 7))

__constant__ float c_adj[49] = {
    1,1,0,0,1,1,1,
    1,1,1,1,1,1,1,
    0,1,1,0,1,0,1,
    0,1,0,1,1,1,1,
    1,1,1,1,1,1,1,
    1,1,0,1,1,1,1,
    1,1,1,1,1,1,1};

__device__ __forceinline__ float gelu_f(float x) {
    return 0.5f * x * (1.0f + erff(x * 0.7071067811865476f));
}
__device__ __forceinline__ float b2f(unsigned short u) {
    unsigned int x = ((unsigned int)u) << 16;
    union { unsigned int i; float f; } c; c.i = x; return c.f;
}
__device__ __forceinline__ unsigned short f2b(float f) {
    __hip_bfloat16 h = __float2bfloat16(f);
    union { __hip_bfloat16 b; unsigned short u; } c; c.b = h; return c.u;
}

__device__ __forceinline__ void gload_lds16(const void* g, void* l) {
    __builtin_amdgcn_global_load_lds(
        (const __attribute__((address_space(1))) unsigned int*)g,
        (__attribute__((address_space(3))) unsigned int*)l, 16, 0, 0);
}

// row mapping: 0: r->r ; 1: r->r*7+6 (ctx rows) ; 2: r->r-r%7+6 (ctx broadcast)
__device__ __forceinline__ int maprow(int r, int mode) {
    if (mode == 1) return r * 7 + 6;
    if (mode == 2) return r - r % 7 + 6;
    return r;
}

// lane's global source for A staging: packed matrix src (KB=32, 1024 cols),
// rowgroup base row0g (multiple of 16), local k-block kblk, lane l.
__device__ __forceinline__ const unsigned short* a_addr(
    const unsigned short* src, int mode, int row0g, int kblk, int l)
{
    if (mode == 0)
        return src + (((size_t)((row0g >> 4) * 32 + kblk)) << 9) + l * 8;
    int rr = maprow(row0g + (l & 15), mode);
    return src + (((size_t)((rr >> 4) * 32 + kblk)) << 9)
               + ((rr & 15) + (l >> 4) * 16) * 8;
}

// ---------------------------------------------------------------------------
// 128x128-tile bf16 MFMA GEMM, BK=64, packed operands.
// C[M x N] = epi(Acat[M x K] @ WT^T); WT packed [N x K] with wKB = K/32.
// Acat cols [0,1024) A1, [1024,2048) A2 (both packed, KB=32).
// Cb packed segmented: seg = c>>10, addr = seg*segStride + PIDX(r, c&1023, 32).
// ---------------------------------------------------------------------------
__global__ __launch_bounds__(256) void gemm128(
    const unsigned short* __restrict__ A1, int a1Mode,
    const unsigned short* __restrict__ A2, int a2Mode,
    const unsigned short* __restrict__ WT, int wKB,
    const float* __restrict__ bias,
    const float* __restrict__ resid,
    float* __restrict__ Cf,
    unsigned short* __restrict__ Cb, size_t segStride,
    int K, int act)
{
    __shared__ short As[128 * 64];   // 16 wave-groups (kb*8+g) x 64 lanes x 8
    __shared__ short Bs[128 * 64];
    const int tid = threadIdx.x;
    const int lane = tid & 63;
    const int w = tid >> 6;
    const int wr = (w >> 1) * 64;
    const int wc = (w & 1) * 64;
    const int wgr = (w >> 1) * 4;
    const int wgc = (w & 1) * 4;
    const int row0 = blockIdx.y * 128;
    const int col0 = blockIdx.x * 128;

    f32x4 acc[4][4] = {};

    for (int k0 = 0; k0 < K; k0 += 64) {
        const unsigned short* srcA; int mode; int kbL;
        if (k0 < 1024) { srcA = A1; mode = a1Mode; kbL = k0 >> 5; }
        else           { srcA = A2; mode = a2Mode; kbL = (k0 - 1024) >> 5; }
        // A: 1024 chunks (8 rowgroups x 2 kblocks x 64 lanes)
        #pragma unroll
        for (int rnd = 0; rnd < 4; ++rnd) {
            int c = rnd * 256 + tid;
            int wg = c >> 6, l = c & 63;
            int g = wg & 7, kb = wg >> 3;
            gload_lds16(a_addr(srcA, mode, row0 + g * 16, kbL + kb, l),
                        &As[c * 8]);
        }
        // B: 1024 chunks
        #pragma unroll
        for (int rnd = 0; rnd < 4; ++rnd) {
            int c = rnd * 256 + tid;
            int wg = c >> 6, l = c & 63;
            int g = wg & 7, kb = wg >> 3;
            gload_lds16(WT + (((size_t)(((col0 >> 4) + g) * wKB + (k0 >> 5) + kb)) << 9)
                           + l * 8,
                        &Bs[c * 8]);
        }
        __syncthreads();
        #pragma unroll
        for (int h = 0; h < 2; ++h) {
            bf16x8 af[4], bf_[4];
            #pragma unroll
            for (int i = 0; i < 4; ++i)
                af[i] = *(const bf16x8*)(&As[((h * 8 + wgr + i) * 64 + lane) * 8]);
            #pragma unroll
            for (int j = 0; j < 4; ++j)
                bf_[j] = *(const bf16x8*)(&Bs[((h * 8 + wgc + j) * 64 + lane) * 8]);
            #pragma unroll
            for (int i = 0; i < 4; ++i)
                #pragma unroll
                for (int j = 0; j < 4; ++j)
                    acc[i][j] = __builtin_amdgcn_mfma_f32_16x16x32_bf16(
                        af[i], bf_[j], acc[i][j], 0, 0, 0);
        }
        __syncthreads();
    }

    const int qrow = (lane >> 4) * 4;
    const int qcol = lane & 15;
    #pragma unroll
    for (int i = 0; i < 4; ++i) {
        int rbase = row0 + wr + i * 16 + qrow;
        #pragma unroll
        for (int j = 0; j < 4; ++j) {
            int c = col0 + wc + j * 16 + qcol;
            float bv = bias ? bias[c] : 0.0f;
            int seg = c >> 10, c0 = c & 1023;
            #pragma unroll
            for (int reg = 0; reg < 4; ++reg) {
                int r = rbase + reg;
                float vv = acc[i][j][reg] + bv;
                if (act) vv = gelu_f(vv);
                if (resid) vv += resid[(size_t)r * 1024 + c];
                if (Cf) Cf[(size_t)r * 1024 + c] = vv;
                if (Cb) Cb[(size_t)seg * segStride + PIDX(r, c0, 32)] = f2b(vv);
            }
        }
    }
}

// ---------------------------------------------------------------------------
// 64x128-tile bf16 MFMA GEMM, BK=64, packed operands. grid: (N/128, M/64).
// Each wave: 64 rows x 32 cols (4x2 frags).
// ---------------------------------------------------------------------------
__global__ __launch_bounds__(256) void gemm64x128(
    const unsigned short* __restrict__ A1, int a1Mode,
    const unsigned short* __restrict__ A2, int a2Mode,
    const unsigned short* __restrict__ WT, int wKB,
    const float* __restrict__ bias,
    const float* __restrict__ resid,
    float* __restrict__ Cf,
    unsigned short* __restrict__ Cb,
    int K, int act)
{
    __shared__ short As[64 * 64];    // 8 wave-groups (kb*4+g)
    __shared__ short Bs[128 * 64];   // 16 wave-groups (kb*8+g)
    const int tid = threadIdx.x;
    const int lane = tid & 63;
    const int w = tid >> 6;
    const int wc = w * 32;
    const int row0 = blockIdx.y * 64;
    const int col0 = blockIdx.x * 128;

    f32x4 acc[4][2] = {};

    for (int k0 = 0; k0 < K; k0 += 64) {
        const unsigned short* srcA; int mode; int kbL;
        if (k0 < 1024) { srcA = A1; mode = a1Mode; kbL = k0 >> 5; }
        else           { srcA = A2; mode = a2Mode; kbL = (k0 - 1024) >> 5; }
        // A: 512 chunks (4 rowgroups x 2 kblocks x 64 lanes)
        #pragma unroll
        for (int rnd = 0; rnd < 2; ++rnd) {
            int c = rnd * 256 + tid;
            int wg = c >> 6, l = c & 63;
            int g = wg & 3, kb = wg >> 2;
            gload_lds16(a_addr(srcA, mode, row0 + g * 16, kbL + kb, l),
                        &As[c * 8]);
        }
        // B: 1024 chunks
        #pragma unroll
        for (int rnd = 0; rnd < 4; ++rnd) {
            int c = rnd * 256 + tid;
            int wg = c >> 6, l = c & 63;
            int g = wg & 7, kb = wg >> 3;
            gload_lds16(WT + (((size_t)(((col0 >> 4) + g) * wKB + (k0 >> 5) + kb)) << 9)
                           + l * 8,
                        &Bs[c * 8]);
        }
        __syncthreads();
        #pragma unroll
        for (int h = 0; h < 2; ++h) {
            bf16x8 af[4], bf_[2];
            #pragma unroll
            for (int i = 0; i < 4; ++i)
                af[i] = *(const bf16x8*)(&As[((h * 4 + i) * 64 + lane) * 8]);
            #pragma unroll
            for (int j = 0; j < 2; ++j)
                bf_[j] = *(const bf16x8*)(&Bs[((h * 8 + w * 2 + j) * 64 + lane) * 8]);
            #pragma unroll
            for (int i = 0; i < 4; ++i)
                #pragma unroll
                for (int j = 0; j < 2; ++j)
                    acc[i][j] = __builtin_amdgcn_mfma_f32_16x16x32_bf16(
                        af[i], bf_[j], acc[i][j], 0, 0, 0);
        }
        __syncthreads();
    }

    const int qrow = (lane >> 4) * 4;
    const int qcol = lane & 15;
    #pragma unroll
    for (int i = 0; i < 4; ++i) {
        int rbase = row0 + i * 16 + qrow;
        #pragma unroll
        for (int j = 0; j < 2; ++j) {
            int c = col0 + wc + j * 16 + qcol;
            float bv = bias ? bias[c] : 0.0f;
            #pragma unroll
            for (int reg = 0; reg < 4; ++reg) {
                int r = rbase + reg;
                float vv = acc[i][j][reg] + bv;
                if (act) vv = gelu_f(vv);
                if (resid) vv += resid[(size_t)r * 1024 + c];
                if (Cf) Cf[(size_t)r * 1024 + c] = vv;
                if (Cb) Cb[PIDX(r, c, 32)] = f2b(vv);
            }
        }
    }
}

// fp32 row-major -> bf16 packed cast (rows x 1024)
__global__ __launch_bounds__(256) void cast_f2b(
    const float* __restrict__ in, unsigned short* __restrict__ out, int n)
{
    int i = (blockIdx.x * 256 + threadIdx.x) * 4;
    if (i >= n) return;
    float4 v = *(const float4*)(in + i);
    ushort4 o;
    o.x = f2b(v.x); o.y = f2b(v.y); o.z = f2b(v.z); o.w = f2b(v.w);
    int r = i >> 10, k = i & 1023;
    *(ushort4*)(out + PIDX(r, k, 32)) = o;
}

// All weight transposes+casts in one dispatch, packed output. grid (32, 64, 9).
__global__ __launch_bounds__(256) void tcast_all(
    const float* __restrict__ Wq, const float* __restrict__ Wk,
    const float* __restrict__ Wv, const float* __restrict__ We1,
    const float* __restrict__ Wu1, const float* __restrict__ Wu2,
    const float* __restrict__ Wi1,
    unsigned short* __restrict__ WT_all, unsigned short* __restrict__ Wu1T,
    unsigned short* __restrict__ Wu2T, unsigned short* __restrict__ Wi1T)
{
    const int z = blockIdx.z;
    const float* src; unsigned short* dst; int R;
    switch (z) {
        case 0: src = Wq;            dst = WT_all;               R = 1024; break;
        case 1: src = Wk;            dst = WT_all + 1024 * 1024; R = 1024; break;
        case 2: src = Wv;            dst = WT_all + 2048 * 1024; R = 1024; break;
        case 3: src = We1;           dst = WT_all + 3072 * 1024; R = 1024; break;
        case 4: src = We1 + 1048576; dst = WT_all + 4096 * 1024; R = 1024; break;
        case 5: src = We1 + 2097152; dst = WT_all + 5120 * 1024; R = 1024; break;
        case 6: src = Wu1;           dst = Wu1T;                 R = 2048; break;
        case 7: src = Wu2;           dst = Wu2T;                 R = 1024; break;
        default: src = Wi1;          dst = Wi1T;                 R = 2048; break;
    }
    const int rt = blockIdx.y * 32;
    if (rt >= R) return;
    const int ct = blockIdx.x * 32;
    __shared__ float t[32][33];
    const int tx = threadIdx.x & 31, ty = threadIdx.x >> 5;
    const int KB = R >> 5;
    #pragma unroll
    for (int s = 0; s < 4; ++s)
        t[ty + s * 8][tx] = src[(size_t)(rt + ty + s * 8) * 1024 + ct + tx];
    __syncthreads();
    #pragma unroll
    for (int s = 0; s < 4; ++s) {
        int nrow = ct + ty + s * 8;   // WT row (N-dim)
        int kcol = rt + tx;           // WT col (K-dim)
        dst[PIDX(nrow, kcol, KB)] = f2b(t[tx][ty + s * 8]);
    }
}

// bias_all[5120] = [bq | bk | bv | 0 | 0]
__global__ void build_bias(const float* __restrict__ bq,
                           const float* __restrict__ bk,
                           const float* __restrict__ bv,
                           float* __restrict__ bias_all)
{
    int i = blockIdx.x * 256 + threadIdx.x;
    if (i >= 5120) return;
    int seg = i >> 10, c = i & 1023;
    float v = 0.f;
    if (seg == 0) v = bq[c];
    else if (seg == 1) v = bk[c];
    else if (seg == 2) v = bv[c];
    bias_all[i] = v;
}

// ---------------------------------------------------------------------------
// One block per (b,n): edge MLP + logits + softmax + messages.
// bf16 inputs/outputs are PACKED. msg may alias la.
// ---------------------------------------------------------------------------
__global__ __launch_bounds__(256) void attn_msg_b(
    const unsigned short* __restrict__ q, const unsigned short* __restrict__ k,
    const unsigned short* __restrict__ v,
    const unsigned short* __restrict__ la, const unsigned short* __restrict__ rb,
    const float* __restrict__ cc,
    const float* __restrict__ We2, const float* __restrict__ be2,
    float* __restrict__ attn_out, unsigned short* __restrict__ msg)
{
    const int bn = blockIdx.x;
    const int b = bn / 7, n = bn % 7;
    const int tid = threadIdx.x;
    const int lane = tid & 63, wv = tid >> 6;
    const int d0 = tid * 4;
    __shared__ float red[8];
    __shared__ float sm[7];

    float qv[4], lav[4], ccv[4], wev[4];
    {
        ushort4 q4 = *(const ushort4*)(q + PIDX(bn, d0, 32));
        ushort4 l4 = *(const ushort4*)(la + PIDX(bn, d0, 32));
        float4 c4 = *(const float4*)(cc + (size_t)b * 1024 + d0);
        float4 w4 = *(const float4*)(We2 + d0);
        qv[0] = b2f(q4.x); qv[1] = b2f(q4.y); qv[2] = b2f(q4.z); qv[3] = b2f(q4.w);
        lav[0] = b2f(l4.x); lav[1] = b2f(l4.y); lav[2] = b2f(l4.z); lav[3] = b2f(l4.w);
        ccv[0] = c4.x; ccv[1] = c4.y; ccv[2] = c4.z; ccv[3] = c4.w;
        wev[0] = w4.x; wev[1] = w4.y; wev[2] = w4.z; wev[3] = w4.w;
    }
    for (int m = 0; m < 7; ++m) {
        ushort4 k4 = *(const ushort4*)(k  + PIDX(b * 7 + m, d0, 32));
        ushort4 r4 = *(const ushort4*)(rb + PIDX(b * 7 + m, d0, 32));
        float s1 = qv[0] * b2f(k4.x) + qv[1] * b2f(k4.y)
                 + qv[2] * b2f(k4.z) + qv[3] * b2f(k4.w);
        float s2 = gelu_f(lav[0] + b2f(r4.x) + ccv[0]) * wev[0]
                 + gelu_f(lav[1] + b2f(r4.y) + ccv[1]) * wev[1]
                 + gelu_f(lav[2] + b2f(r4.z) + ccv[2]) * wev[2]
                 + gelu_f(lav[3] + b2f(r4.w) + ccv[3]) * wev[3];
        #pragma unroll
        for (int off = 32; off > 0; off >>= 1) {
            s1 += __shfl_down(s1, off);
            s2 += __shfl_down(s2, off);
        }
        if (lane == 0) { red[wv * 2] = s1; red[wv * 2 + 1] = s2; }
        __syncthreads();
        if (tid == 0) {
            float d1 = red[0] + red[2] + red[4] + red[6];
            float d2 = red[1] + red[3] + red[5] + red[7];
            sm[m] = d1 * (1.0f / 32.0f) + d2 + be2[0]
                  + (c_adj[n * 7 + m] - 1.0f) * 10000.0f;
        }
        __syncthreads();
    }
    if (tid == 0) {
        float mx = sm[0];
        #pragma unroll
        for (int m = 1; m < 7; ++m) mx = fmaxf(mx, sm[m]);
        float e[7], s = 0.f;
        #pragma unroll
        for (int m = 0; m < 7; ++m) { e[m] = expf(sm[m] - mx); s += e[m]; }
        float inv = 1.0f / s;
        #pragma unroll
        for (int m = 0; m < 7; ++m) {
            float wgt = e[m] * inv;
            sm[m] = wgt;
            attn_out[(size_t)bn * 7 + m] = wgt;
        }
    }
    __syncthreads();
    float wr_[7];
    #pragma unroll
    for (int m = 0; m < 7; ++m) wr_[m] = sm[m];
    float s0 = 0.f, s1 = 0.f, s2 = 0.f, s3 = 0.f;
    #pragma unroll
    for (int m = 0; m < 7; ++m) {
        ushort4 v4 = *(const ushort4*)(v + PIDX(b * 7 + m, d0, 32));
        s0 += wr_[m] * b2f(v4.x); s1 += wr_[m] * b2f(v4.y);
        s2 += wr_[m] * b2f(v4.z); s3 += wr_[m] * b2f(v4.w);
    }
    ushort4 o;
    o.x = f2b(s0); o.y = f2b(s1); o.z = f2b(s2); o.w = f2b(s3);
    *(ushort4*)(msg + PIDX(bn, d0, 32)) = o;
}

// imp_logits[r] = dot(H[r,:], w2) + b2[0]   (H bf16 packed)
__global__ __launch_bounds__(256) void row_dot_b(
    const unsigned short* __restrict__ H, const float* __restrict__ w2,
    const float* __restrict__ b2, float* __restrict__ out)
{
    const int r = blockIdx.x;
    const int tid = threadIdx.x;
    const int lane = tid & 63, wv = tid >> 6;
    __shared__ float red[4];
    const int d0 = tid * 4;
    ushort4 h4 = *(const ushort4*)(H + PIDX(r, d0, 32));
    float4 w4 = *(const float4*)(w2 + d0);
    float s = b2f(h4.x) * w4.x + b2f(h4.y) * w4.y
            + b2f(h4.z) * w4.z + b2f(h4.w) * w4.w;
    #pragma unroll
    for (int off = 32; off > 0; off >>= 1) s += __shfl_down(s, off);
    if (lane == 0) red[wv] = s;
    __syncthreads();
    if (tid == 0) out[r] = red[0] + red[1] + red[2] + red[3] + b2[0];
}

// per-b: softmax over N, cap/redistribute, imp; fused = sum_n imp*updated
__global__ __launch_bounds__(256) void imp_fused_k(
    const float* __restrict__ logits, const float* __restrict__ upd,
    float* __restrict__ imp_out, float* __restrict__ fused_out)
{
    const int b = blockIdx.x;
    const int tid = threadIdx.x;
    __shared__ float w[7];
    if (tid == 0) {
        float l[7], e[7];
        float mx = -1e30f;
        for (int i = 0; i < 7; ++i) { l[i] = logits[b * 7 + i]; mx = fmaxf(mx, l[i]); }
        float s = 0.f;
        for (int i = 0; i < 7; ++i) { e[i] = expf(l[i] - mx); s += e[i]; }
        float inv = 1.0f / s;
        float imp[7];
        for (int i = 0; i < 7; ++i) imp[i] = e[i] * inv;
        const float cap[7] = {1.f, 1.f, 1.f, 0.26f, 1.f, 1.f, 0.24f};
        const float fr[7]  = {1.f, 1.f, 1.f, 0.f,   1.f, 1.f, 0.f};
        float capped[7], capsum = 0.f, fmass = 0.f;
        for (int i = 0; i < 7; ++i) {
            capped[i] = fminf(imp[i], cap[i]);
            capsum += capped[i];
            fmass += imp[i] * fr[i];
        }
        float residual = fmaxf(1.0f - capsum, 0.0f);
        float redis[7], rs = 0.f;
        for (int i = 0; i < 7; ++i) {
            float fs = (fmass > 1e-6f) ? imp[i] * fr[i] / fmaxf(fmass, 1e-6f)
                                       : fr[i] * 0.2f;
            redis[i] = capped[i] + fs * residual;
            rs += redis[i];
        }
        float invr = 1.0f / fmaxf(rs, 1e-6f);
        for (int i = 0; i < 7; ++i) {
            float wi = redis[i] * invr;
            w[i] = wi;
            imp_out[b * 7 + i] = wi;
        }
    }
    __syncthreads();
    float wr[7];
    #pragma unroll
    for (int i = 0; i < 7; ++i) wr[i] = w[i];
    #pragma unroll
    for (int j = 0; j < 4; ++j) {
        int d = tid + j * 256;
        float s = 0.f;
        #pragma unroll
        for (int nn2 = 0; nn2 < 7; ++nn2)
            s += wr[nn2] * upd[(size_t)(b * 7 + nn2) * 1024 + d];
        fused_out[(size_t)b * 1024 + d] = s;
    }
}

__global__ void zero_acc(float* a) { if (threadIdx.x < 4) a[threadIdx.x] = 0.f; }

__global__ __launch_bounds__(256) void physics_k(
    const float* __restrict__ upd, const float* __restrict__ fused,
    float* __restrict__ accums)
{
    const int b = blockIdx.x;
    const int tid = threadIdx.x;
    const int lane = tid & 63, wv = tid >> 6;
    __shared__ float u[7][1024];
    __shared__ float f[1024];
    __shared__ float wred[4][36];
    for (int idx = tid; idx < 7 * 1024; idx += 256)
        u[idx >> 10][idx & 1023] = upd[(size_t)b * 7168 + idx];
    for (int d = tid; d < 1024; d += 256)
        f[d] = fused[(size_t)b * 1024 + d];
    __syncthreads();

    float vals[36];
    #pragma unroll
    for (int i = 0; i < 36; ++i) vals[i] = 0.f;
    for (int d = tid; d < 1024; d += 256) {
        float x[7];
        #pragma unroll
        for (int n = 0; n < 7; ++n) x[n] = u[n][d];
        float fv = f[d];
        int idx = 0;
        #pragma unroll
        for (int n = 0; n < 7; ++n) {
            #pragma unroll
            for (int m = n; m < 7; ++m) vals[idx++] += x[n] * x[m];
        }
        #pragma unroll
        for (int n = 0; n < 7; ++n) vals[28 + n] += x[n] * fv;
        vals[35] += fv * fv;
    }
    #pragma unroll
    for (int i = 0; i < 36; ++i) {
        float s = vals[i];
        #pragma unroll
        for (int off = 32; off > 0; off >>= 1) s += __shfl_down(s, off);
        if (lane == 0) wred[wv][i] = s;
    }
    __syncthreads();
    if (tid == 0) {
        float tv[36];
        for (int i = 0; i < 36; ++i)
            tv[i] = wred[0][i] + wred[1][i] + wred[2][i] + wred[3][i];
        auto didx = [](int n, int m) -> int {
            if (n > m) { int t = n; n = m; m = t; }
            return n * 7 - n * (n - 1) / 2 + (m - n);
        };
        float norms[7];
        for (int n = 0; n < 7; ++n) norms[n] = sqrtf(tv[didx(n, n)]);
        float e = 0.f, nl = 0.f;
        for (int n = 0; n < 7; ++n)
            for (int m = 0; m < 7; ++m) {
                float cos_ = tv[didx(n, m)] / fmaxf(norms[n] * norms[m], 1e-8f);
                float adj = c_adj[n * 7 + m];
                e += (1.0f - cos_) * adj;
                if (adj == 0.0f && n != m) nl += fmaxf(cos_ - 0.35f, 0.0f);
            }
        float fnorm = sqrtf(tv[35]);
        float al = 0.f;
        for (int n = 0; n < 7; ++n) {
            float cosn = tv[28 + n] /
                         (fmaxf(norms[n], 1e-12f) * fmaxf(fnorm, 1e-12f));
            al += 1.0f - cosn;
        }
        atomicAdd(&accums[0], e);
        atomicAdd(&accums[1], nl);
        atomicAdd(&accums[2], al);
    }
}

__global__ void finalize_k(const float* __restrict__ a,
                           float* __restrict__ phys_o,
                           float* __restrict__ align_o)
{
    phys_o[0]  = a[0] / 41.0f + 0.5f * (a[1] / 8.0f);
    align_o[0] = a[2] * (1.0f / 7168.0f);
}

extern "C" void kernel_launch(void* const* d_in, const int* in_sizes, int n_in,
                              void* d_out, int out_size, void* d_ws, size_t ws_size,
                              hipStream_t stream)
{
    const float* nodes = (const float*)d_in[0];
    const float* Wq  = (const float*)d_in[1];
    const float* bq  = (const float*)d_in[2];
    const float* Wk  = (const float*)d_in[3];
    const float* bk  = (const float*)d_in[4];
    const float* Wv  = (const float*)d_in[5];
    const float* bv  = (const float*)d_in[6];
    const float* We1 = (const float*)d_in[7];
    const float* be1 = (const float*)d_in[8];
    const float* We2 = (const float*)d_in[9];
    const float* be2 = (const float*)d_in[10];
    const float* Wu1 = (const float*)d_in[11];
    const float* bu1 = (const float*)d_in[12];
    const float* Wu2 = (const float*)d_in[13];
    const float* bu2 = (const float*)d_in[14];
    const float* Wi1 = (const float*)d_in[15];
    const float* bi1 = (const float*)d_in[16];
    const float* Wi2 = (const float*)d_in[17];
    const float* bi2 = (const float*)d_in[18];

    float* out = (float*)d_out;
    float* fused_o = out;                            // 1,048,576
    float* upd_o   = out + 1048576;                  // 7,340,032
    float* imp_o   = out + 1048576 + 7340032;        // 7,168
    float* attn_o  = imp_o + 7168;                   // 50,176
    float* phys_o  = attn_o + 50176;                 // 1
    float* align_o = phys_o + 1;                     // 1

    const size_t BIG = 7340032;   // B*N*D
    const size_t MEG = 1048576;   // D*D
    char* p = (char*)d_ws;
    unsigned short* nodes_b = (unsigned short*)p; p += BIG * 2;
    unsigned short* qb      = (unsigned short*)p; p += BIG * 2;   // seg 0; reused: h_u
    unsigned short* kb      = (unsigned short*)p; p += BIG * 2;   // seg 1; reused: upd_b
    unsigned short* vb      = (unsigned short*)p; p += BIG * 2;   // seg 2; reused: h_i
    unsigned short* lab     = (unsigned short*)p; p += BIG * 2;   // seg 3; reused: msg
    unsigned short* rbb     = (unsigned short*)p; p += BIG * 2;   // seg 4
    unsigned short* WT_all  = (unsigned short*)p; p += (size_t)6144 * 1024 * 2;
    unsigned short* Wu1T    = (unsigned short*)p; p += 2 * MEG * 2;
    unsigned short* Wu2T    = (unsigned short*)p; p += MEG * 2;
    unsigned short* Wi1T    = (unsigned short*)p; p += 2 * MEG * 2;
    float* bias_all = (float*)p; p += 5120 * 4;
    float* ccf = (float*)p; p += MEG * 4;
    float* il  = (float*)p; p += 7168 * 4;
    float* acc = (float*)p; p += 4 * 4;
    unsigned short* msgb = lab;   // alias: safe (see attn_msg_b)
    unsigned short* hub  = qb;
    unsigned short* updb = kb;
    unsigned short* hib  = vb;

    dim3 blk(256);

    // prep (packed bf16 everywhere)
    cast_f2b<<<dim3(7168), blk, 0, stream>>>(nodes, nodes_b, 7340032);
    tcast_all<<<dim3(32, 64, 9), blk, 0, stream>>>(Wq, Wk, Wv, We1, Wu1, Wu2, Wi1,
                                                   WT_all, Wu1T, Wu2T, Wi1T);
    build_bias<<<dim3(20), blk, 0, stream>>>(bq, bk, bv, bias_all);

    // fused q|k|v|la|rb : N=5120, segmented packed bf16 out into qb..rbb
    gemm128<<<dim3(40, 56), blk, 0, stream>>>(
        nodes_b, 0, nullptr, 0, WT_all, 32, bias_all, nullptr,
        nullptr, qb, BIG, 1024, 0);

    // cc = nodes[:,-1] @ Wc + be1 (fp32 row-major out), WcT = WT_all seg 5
    gemm64x128<<<dim3(8, 16), blk, 0, stream>>>(
        nodes_b, 1, nullptr, 0, WT_all + (size_t)5 * MEG, 32, be1, nullptr,
        ccf, nullptr, 1024, 0);

    // attention + messages (msg overwrites la)
    attn_msg_b<<<dim3(7168), blk, 0, stream>>>(qb, kb, vb, lab, rbb, ccf, We2, be2,
                                               attn_o, msgb);

    // h_u = gelu([nodes|msg] @ Wu1 + bu1)
    gemm64x128<<<dim3(8, 112), blk, 0, stream>>>(
        nodes_b, 0, msgb, 0, Wu1T, 64, bu1, nullptr, nullptr, hub, 2048, 1);
    // updated = h_u @ Wu2 + bu2 + nodes (fp32 row-major out + packed bf16 copy)
    gemm64x128<<<dim3(8, 112), blk, 0, stream>>>(
        hub, 0, nullptr, 0, Wu2T, 32, bu2, nodes, upd_o, updb, 1024, 0);
    // h_i = gelu([updated|ctx] @ Wi1 + bi1)
    gemm64x128<<<dim3(8, 112), blk, 0, stream>>>(
        updb, 0, updb, 2, Wi1T, 64, bi1, nullptr, nullptr, hib, 2048, 1);

    // tail
    row_dot_b<<<dim3(7168), blk, 0, stream>>>(hib, Wi2, bi2, il);
    imp_fused_k<<<dim3(1024), blk, 0, stream>>>(il, upd_o, imp_o, fused_o);
    zero_acc<<<1, 64, 0, stream>>>(acc);
    physics_k<<<dim3(1024), blk, 0, stream>>>(upd_o, fused_o, acc);
    finalize_k<<<1, 1, 0, stream>>>(acc, phys_o, align_o);
}

// Round 7
// 598.882 us; speedup vs baseline: 1.2479x; 1.2479x over previous
//
#include <hip/hip_runtime.h>
#include <hip/hip_bf16.h>

// PhysicsGraphFusion: B=1024, N=7, D=1024
// Outputs (flat): fused (B*D), updated (B*N*D), imp (B*N), attn (B*N*N), phys (1), align (1)
//
// "Fragment-tile packed" bf16 layout (GEMM<->GEMM edges ONLY): element (r,k),
// KB = cols/32:  ((r>>4)*KB + (k>>5))*512 + ((k>>3)&3)*128 + (r&15)*8 + (k&7)
// -> wave's 64 x 16B DMA chunks contiguous in HBM AND lane-linear in LDS.
// Packed: nodes_b, weights, h_u, upd_b.  Row-major: q,k,v,la,rb,msg,h_i
// (single-row consumers: packed would cause 4x HBM over-fetch — round 6 lesson).

typedef __attribute__((ext_vector_type(8))) short bf16x8;
typedef __attribute__((ext_vector_type(4))) float f32x4;

#define PIDX(r, kk, KB) \
    ((((size_t)(((r) >> 4) * (KB) + ((kk) >> 5))) << 9) + \
     ((((((kk) >> 3) & 3) << 4) + ((r) & 15)) << 3) + ((kk) & 7))

__constant__ float c_adj[49] = {
    1,1,0,0,1,1,1,
    1,1,1,1,1,1,1,
    0,1,1,0,1,0,1,
    0,1,0,1,1,1,1,
    1,1,1,1,1,1,1,
    1,1,0,1,1,1,1,
    1,1,1,1,1,1,1};

__device__ __forceinline__ float gelu_f(float x) {
    return 0.5f * x * (1.0f + erff(x * 0.7071067811865476f));
}
__device__ __forceinline__ float b2f(unsigned short u) {
    unsigned int x = ((unsigned int)u) << 16;
    union { unsigned int i; float f; } c; c.i = x; return c.f;
}
__device__ __forceinline__ unsigned short f2b(float f) {
    __hip_bfloat16 h = __float2bfloat16(f);
    union { __hip_bfloat16 b; unsigned short u; } c; c.b = h; return c.u;
}

__device__ __forceinline__ void gload_lds16(const void* g, void* l) {
    __builtin_amdgcn_global_load_lds(
        (const __attribute__((address_space(1))) unsigned int*)g,
        (__attribute__((address_space(3))) unsigned int*)l, 16, 0, 0);
}

// row mapping: 1: r->r*7+6 (ctx rows) ; 2: r->r-r%7+6 (ctx broadcast)
__device__ __forceinline__ int maprow(int r, int mode) {
    if (mode == 1) return r * 7 + 6;
    if (mode == 2) return r - r % 7 + 6;
    return r;
}

// lane's global source for A staging (A always 1024 cols, KB=32 if packed).
// mode 0: packed direct; 1/2: packed + row mapping; 3: row-major direct.
__device__ __forceinline__ const unsigned short* a_addr(
    const unsigned short* src, int mode, int row0g, int kblk, int l)
{
    if (mode == 0)
        return src + (((size_t)((row0g >> 4) * 32 + kblk)) << 9) + l * 8;
    if (mode == 3) {
        int rr = row0g + (l & 15);
        return src + (size_t)rr * 1024 + kblk * 32 + (l >> 4) * 8;
    }
    int rr = maprow(row0g + (l & 15), mode);
    return src + (((size_t)((rr >> 4) * 32 + kblk)) << 9)
               + ((rr & 15) + (l >> 4) * 16) * 8;
}

// ---------------------------------------------------------------------------
// 128x128-tile bf16 MFMA GEMM, BK=64. WT packed [N x K], wKB = K/32.
// Cb row-major segmented: seg = c>>10, addr = seg*segStride + r*1024 + (c&1023).
// ---------------------------------------------------------------------------
__global__ __launch_bounds__(256) void gemm128(
    const unsigned short* __restrict__ A1, int a1Mode,
    const unsigned short* __restrict__ A2, int a2Mode,
    const unsigned short* __restrict__ WT, int wKB,
    const float* __restrict__ bias,
    const float* __restrict__ resid,
    float* __restrict__ Cf,
    unsigned short* __restrict__ Cb, size_t segStride,
    int K, int act)
{
    __shared__ short As[128 * 64];   // 16 wave-groups (kb*8+g) x 64 lanes x 8
    __shared__ short Bs[128 * 64];
    const int tid = threadIdx.x;
    const int lane = tid & 63;
    const int w = tid >> 6;
    const int wr = (w >> 1) * 64;
    const int wc = (w & 1) * 64;
    const int wgr = (w >> 1) * 4;
    const int wgc = (w & 1) * 4;
    const int row0 = blockIdx.y * 128;
    const int col0 = blockIdx.x * 128;

    f32x4 acc[4][4] = {};

    for (int k0 = 0; k0 < K; k0 += 64) {
        const unsigned short* srcA; int mode; int kbL;
        if (k0 < 1024) { srcA = A1; mode = a1Mode; kbL = k0 >> 5; }
        else           { srcA = A2; mode = a2Mode; kbL = (k0 - 1024) >> 5; }
        #pragma unroll
        for (int rnd = 0; rnd < 4; ++rnd) {
            int c = rnd * 256 + tid;
            int wg = c >> 6, l = c & 63;
            int g = wg & 7, kb = wg >> 3;
            gload_lds16(a_addr(srcA, mode, row0 + g * 16, kbL + kb, l),
                        &As[c * 8]);
        }
        #pragma unroll
        for (int rnd = 0; rnd < 4; ++rnd) {
            int c = rnd * 256 + tid;
            int wg = c >> 6, l = c & 63;
            int g = wg & 7, kb = wg >> 3;
            gload_lds16(WT + (((size_t)(((col0 >> 4) + g) * wKB + (k0 >> 5) + kb)) << 9)
                           + l * 8,
                        &Bs[c * 8]);
        }
        __syncthreads();
        #pragma unroll
        for (int h = 0; h < 2; ++h) {
            bf16x8 af[4], bf_[4];
            #pragma unroll
            for (int i = 0; i < 4; ++i)
                af[i] = *(const bf16x8*)(&As[((h * 8 + wgr + i) * 64 + lane) * 8]);
            #pragma unroll
            for (int j = 0; j < 4; ++j)
                bf_[j] = *(const bf16x8*)(&Bs[((h * 8 + wgc + j) * 64 + lane) * 8]);
            #pragma unroll
            for (int i = 0; i < 4; ++i)
                #pragma unroll
                for (int j = 0; j < 4; ++j)
                    acc[i][j] = __builtin_amdgcn_mfma_f32_16x16x32_bf16(
                        af[i], bf_[j], acc[i][j], 0, 0, 0);
        }
        __syncthreads();
    }

    const int qrow = (lane >> 4) * 4;
    const int qcol = lane & 15;
    #pragma unroll
    for (int i = 0; i < 4; ++i) {
        int rbase = row0 + wr + i * 16 + qrow;
        #pragma unroll
        for (int j = 0; j < 4; ++j) {
            int c = col0 + wc + j * 16 + qcol;
            float bv = bias ? bias[c] : 0.0f;
            int seg = c >> 10, c0 = c & 1023;
            #pragma unroll
            for (int reg = 0; reg < 4; ++reg) {
                int r = rbase + reg;
                float vv = acc[i][j][reg] + bv;
                if (act) vv = gelu_f(vv);
                if (resid) vv += resid[(size_t)r * 1024 + c];
                if (Cf) Cf[(size_t)r * 1024 + c] = vv;
                if (Cb) Cb[(size_t)seg * segStride + (size_t)r * 1024 + c0] = f2b(vv);
            }
        }
    }
}

// ---------------------------------------------------------------------------
// 64x128-tile bf16 MFMA GEMM, BK=64. grid: (N/128, M/64).
// Cb: packed if cbPacked else row-major (1024 cols).
// ---------------------------------------------------------------------------
__global__ __launch_bounds__(256) void gemm64x128(
    const unsigned short* __restrict__ A1, int a1Mode,
    const unsigned short* __restrict__ A2, int a2Mode,
    const unsigned short* __restrict__ WT, int wKB,
    const float* __restrict__ bias,
    const float* __restrict__ resid,
    float* __restrict__ Cf,
    unsigned short* __restrict__ Cb, int cbPacked,
    int K, int act)
{
    __shared__ short As[64 * 64];    // 8 wave-groups (kb*4+g)
    __shared__ short Bs[128 * 64];   // 16 wave-groups (kb*8+g)
    const int tid = threadIdx.x;
    const int lane = tid & 63;
    const int w = tid >> 6;
    const int wc = w * 32;
    const int row0 = blockIdx.y * 64;
    const int col0 = blockIdx.x * 128;

    f32x4 acc[4][2] = {};

    for (int k0 = 0; k0 < K; k0 += 64) {
        const unsigned short* srcA; int mode; int kbL;
        if (k0 < 1024) { srcA = A1; mode = a1Mode; kbL = k0 >> 5; }
        else           { srcA = A2; mode = a2Mode; kbL = (k0 - 1024) >> 5; }
        #pragma unroll
        for (int rnd = 0; rnd < 2; ++rnd) {
            int c = rnd * 256 + tid;
            int wg = c >> 6, l = c & 63;
            int g = wg & 3, kb = wg >> 2;
            gload_lds16(a_addr(srcA, mode, row0 + g * 16, kbL + kb, l),
                        &As[c * 8]);
        }
        #pragma unroll
        for (int rnd = 0; rnd < 4; ++rnd) {
            int c = rnd * 256 + tid;
            int wg = c >> 6, l = c & 63;
            int g = wg & 7, kb = wg >> 3;
            gload_lds16(WT + (((size_t)(((col0 >> 4) + g) * wKB + (k0 >> 5) + kb)) << 9)
                           + l * 8,
                        &Bs[c * 8]);
        }
        __syncthreads();
        #pragma unroll
        for (int h = 0; h < 2; ++h) {
            bf16x8 af[4], bf_[2];
            #pragma unroll
            for (int i = 0; i < 4; ++i)
                af[i] = *(const bf16x8*)(&As[((h * 4 + i) * 64 + lane) * 8]);
            #pragma unroll
            for (int j = 0; j < 2; ++j)
                bf_[j] = *(const bf16x8*)(&Bs[((h * 8 + w * 2 + j) * 64 + lane) * 8]);
            #pragma unroll
            for (int i = 0; i < 4; ++i)
                #pragma unroll
                for (int j = 0; j < 2; ++j)
                    acc[i][j] = __builtin_amdgcn_mfma_f32_16x16x32_bf16(
                        af[i], bf_[j], acc[i][j], 0, 0, 0);
        }
        __syncthreads();
    }

    const int qrow = (lane >> 4) * 4;
    const int qcol = lane & 15;
    #pragma unroll
    for (int i = 0; i < 4; ++i) {
        int rbase = row0 + i * 16 + qrow;
        #pragma unroll
        for (int j = 0; j < 2; ++j) {
            int c = col0 + wc + j * 16 + qcol;
            float bv = bias ? bias[c] : 0.0f;
            #pragma unroll
            for (int reg = 0; reg < 4; ++reg) {
                int r = rbase + reg;
                float vv = acc[i][j][reg] + bv;
                if (act) vv = gelu_f(vv);
                if (resid) vv += resid[(size_t)r * 1024 + c];
                if (Cf) Cf[(size_t)r * 1024 + c] = vv;
                if (Cb) {
                    if (cbPacked) Cb[PIDX(r, c, 32)] = f2b(vv);
                    else          Cb[(size_t)r * 1024 + c] = f2b(vv);
                }
            }
        }
    }
}

// fp32 row-major -> bf16 packed cast (rows x 1024)
__global__ __launch_bounds__(256) void cast_f2b(
    const float* __restrict__ in, unsigned short* __restrict__ out, int n)
{
    int i = (blockIdx.x * 256 + threadIdx.x) * 4;
    if (i >= n) return;
    float4 v = *(const float4*)(in + i);
    ushort4 o;
    o.x = f2b(v.x); o.y = f2b(v.y); o.z = f2b(v.z); o.w = f2b(v.w);
    int r = i >> 10, k = i & 1023;
    *(ushort4*)(out + PIDX(r, k, 32)) = o;
}

// All weight transposes+casts in one dispatch, packed output. grid (32, 64, 9).
__global__ __launch_bounds__(256) void tcast_all(
    const float* __restrict__ Wq, const float* __restrict__ Wk,
    const float* __restrict__ Wv, const float* __restrict__ We1,
    const float* __restrict__ Wu1, const float* __restrict__ Wu2,
    const float* __restrict__ Wi1,
    unsigned short* __restrict__ WT_all, unsigned short* __restrict__ Wu1T,
    unsigned short* __restrict__ Wu2T, unsigned short* __restrict__ Wi1T)
{
    const int z = blockIdx.z;
    const float* src; unsigned short* dst; int R;
    switch (z) {
        case 0: src = Wq;            dst = WT_all;               R = 1024; break;
        case 1: src = Wk;            dst = WT_all + 1024 * 1024; R = 1024; break;
        case 2: src = Wv;            dst = WT_all + 2048 * 1024; R = 1024; break;
        case 3: src = We1;           dst = WT_all + 3072 * 1024; R = 1024; break;
        case 4: src = We1 + 1048576; dst = WT_all + 4096 * 1024; R = 1024; break;
        case 5: src = We1 + 2097152; dst = WT_all + 5120 * 1024; R = 1024; break;
        case 6: src = Wu1;           dst = Wu1T;                 R = 2048; break;
        case 7: src = Wu2;           dst = Wu2T;                 R = 1024; break;
        default: src = Wi1;          dst = Wi1T;                 R = 2048; break;
    }
    const int rt = blockIdx.y * 32;
    if (rt >= R) return;
    const int ct = blockIdx.x * 32;
    __shared__ float t[32][33];
    const int tx = threadIdx.x & 31, ty = threadIdx.x >> 5;
    const int KB = R >> 5;
    #pragma unroll
    for (int s = 0; s < 4; ++s)
        t[ty + s * 8][tx] = src[(size_t)(rt + ty + s * 8) * 1024 + ct + tx];
    __syncthreads();
    #pragma unroll
    for (int s = 0; s < 4; ++s) {
        int nrow = ct + ty + s * 8;   // WT row (N-dim)
        int kcol = rt + tx;           // WT col (K-dim)
        dst[PIDX(nrow, kcol, KB)] = f2b(t[tx][ty + s * 8]);
    }
}

// bias_all[5120] = [bq | bk | bv | 0 | 0]
__global__ void build_bias(const float* __restrict__ bq,
                           const float* __restrict__ bk,
                           const float* __restrict__ bv,
                           float* __restrict__ bias_all)
{
    int i = blockIdx.x * 256 + threadIdx.x;
    if (i >= 5120) return;
    int seg = i >> 10, c = i & 1023;
    float v = 0.f;
    if (seg == 0) v = bq[c];
    else if (seg == 1) v = bk[c];
    else if (seg == 2) v = bv[c];
    bias_all[i] = v;
}

// ---------------------------------------------------------------------------
// One block per (b,n): edge MLP + logits + softmax + messages.
// bf16 inputs/outputs ROW-MAJOR. msg may alias la.
// ---------------------------------------------------------------------------
__global__ __launch_bounds__(256) void attn_msg_b(
    const unsigned short* __restrict__ q, const unsigned short* __restrict__ k,
    const unsigned short* __restrict__ v,
    const unsigned short* __restrict__ la, const unsigned short* __restrict__ rb,
    const float* __restrict__ cc,
    const float* __restrict__ We2, const float* __restrict__ be2,
    float* __restrict__ attn_out, unsigned short* __restrict__ msg)
{
    const int bn = blockIdx.x;
    const int b = bn / 7, n = bn % 7;
    const int tid = threadIdx.x;
    const int lane = tid & 63, wv = tid >> 6;
    const int d0 = tid * 4;
    __shared__ float red[8];
    __shared__ float sm[7];

    float qv[4], lav[4], ccv[4], wev[4];
    {
        ushort4 q4 = *(const ushort4*)(q + (size_t)bn * 1024 + d0);
        ushort4 l4 = *(const ushort4*)(la + (size_t)bn * 1024 + d0);
        float4 c4 = *(const float4*)(cc + (size_t)b * 1024 + d0);
        float4 w4 = *(const float4*)(We2 + d0);
        qv[0] = b2f(q4.x); qv[1] = b2f(q4.y); qv[2] = b2f(q4.z); qv[3] = b2f(q4.w);
        lav[0] = b2f(l4.x); lav[1] = b2f(l4.y); lav[2] = b2f(l4.z); lav[3] = b2f(l4.w);
        ccv[0] = c4.x; ccv[1] = c4.y; ccv[2] = c4.z; ccv[3] = c4.w;
        wev[0] = w4.x; wev[1] = w4.y; wev[2] = w4.z; wev[3] = w4.w;
    }
    for (int m = 0; m < 7; ++m) {
        ushort4 k4 = *(const ushort4*)(k  + (size_t)(b * 7 + m) * 1024 + d0);
        ushort4 r4 = *(const ushort4*)(rb + (size_t)(b * 7 + m) * 1024 + d0);
        float s1 = qv[0] * b2f(k4.x) + qv[1] * b2f(k4.y)
                 + qv[2] * b2f(k4.z) + qv[3] * b2f(k4.w);
        float s2 = gelu_f(lav[0] + b2f(r4.x) + ccv[0]) * wev[0]
                 + gelu_f(lav[1] + b2f(r4.y) + ccv[1]) * wev[1]
                 + gelu_f(lav[2] + b2f(r4.z) + ccv[2]) * wev[2]
                 + gelu_f(lav[3] + b2f(r4.w) + ccv[3]) * wev[3];
        #pragma unroll
        for (int off = 32; off > 0; off >>= 1) {
            s1 += __shfl_down(s1, off);
            s2 += __shfl_down(s2, off);
        }
        if (lane == 0) { red[wv * 2] = s1; red[wv * 2 + 1] = s2; }
        __syncthreads();
        if (tid == 0) {
            float d1 = red[0] + red[2] + red[4] + red[6];
            float d2 = red[1] + red[3] + red[5] + red[7];
            sm[m] = d1 * (1.0f / 32.0f) + d2 + be2[0]
                  + (c_adj[n * 7 + m] - 1.0f) * 10000.0f;
        }
        __syncthreads();
    }
    if (tid == 0) {
        float mx = sm[0];
        #pragma unroll
        for (int m = 1; m < 7; ++m) mx = fmaxf(mx, sm[m]);
        float e[7], s = 0.f;
        #pragma unroll
        for (int m = 0; m < 7; ++m) { e[m] = expf(sm[m] - mx); s += e[m]; }
        float inv = 1.0f / s;
        #pragma unroll
        for (int m = 0; m < 7; ++m) {
            float wgt = e[m] * inv;
            sm[m] = wgt;
            attn_out[(size_t)bn * 7 + m] = wgt;
        }
    }
    __syncthreads();
    float wr_[7];
    #pragma unroll
    for (int m = 0; m < 7; ++m) wr_[m] = sm[m];
    float s0 = 0.f, s1 = 0.f, s2 = 0.f, s3 = 0.f;
    #pragma unroll
    for (int m = 0; m < 7; ++m) {
        ushort4 v4 = *(const ushort4*)(v + (size_t)(b * 7 + m) * 1024 + d0);
        s0 += wr_[m] * b2f(v4.x); s1 += wr_[m] * b2f(v4.y);
        s2 += wr_[m] * b2f(v4.z); s3 += wr_[m] * b2f(v4.w);
    }
    ushort4 o;
    o.x = f2b(s0); o.y = f2b(s1); o.z = f2b(s2); o.w = f2b(s3);
    *(ushort4*)(msg + (size_t)bn * 1024 + d0) = o;
}

// imp_logits[r] = dot(H[r,:], w2) + b2[0]   (H bf16 row-major)
__global__ __launch_bounds__(256) void row_dot_b(
    const unsigned short* __restrict__ H, const float* __restrict__ w2,
    const float* __restrict__ b2, float* __restrict__ out)
{
    const int r = blockIdx.x;
    const int tid = threadIdx.x;
    const int lane = tid & 63, wv = tid >> 6;
    __shared__ float red[4];
    const int d0 = tid * 4;
    ushort4 h4 = *(const ushort4*)(H + (size_t)r * 1024 + d0);
    float4 w4 = *(const float4*)(w2 + d0);
    float s = b2f(h4.x) * w4.x + b2f(h4.y) * w4.y
            + b2f(h4.z) * w4.z + b2f(h4.w) * w4.w;
    #pragma unroll
    for (int off = 32; off > 0; off >>= 1) s += __shfl_down(s, off);
    if (lane == 0) red[wv] = s;
    __syncthreads();
    if (tid == 0) out[r] = red[0] + red[1] + red[2] + red[3] + b2[0];
}

// per-b: softmax over N, cap/redistribute, imp; fused = sum_n imp*updated
__global__ __launch_bounds__(256) void imp_fused_k(
    const float* __restrict__ logits, const float* __restrict__ upd,
    float* __restrict__ imp_out, float* __restrict__ fused_out)
{
    const int b = blockIdx.x;
    const int tid = threadIdx.x;
    __shared__ float w[7];
    if (tid == 0) {
        float l[7], e[7];
        float mx = -1e30f;
        for (int i = 0; i < 7; ++i) { l[i] = logits[b * 7 + i]; mx = fmaxf(mx, l[i]); }
        float s = 0.f;
        for (int i = 0; i < 7; ++i) { e[i] = expf(l[i] - mx); s += e[i]; }
        float inv = 1.0f / s;
        float imp[7];
        for (int i = 0; i < 7; ++i) imp[i] = e[i] * inv;
        const float cap[7] = {1.f, 1.f, 1.f, 0.26f, 1.f, 1.f, 0.24f};
        const float fr[7]  = {1.f, 1.f, 1.f, 0.f,   1.f, 1.f, 0.f};
        float capped[7], capsum = 0.f, fmass = 0.f;
        for (int i = 0; i < 7; ++i) {
            capped[i] = fminf(imp[i], cap[i]);
            capsum += capped[i];
            fmass += imp[i] * fr[i];
        }
        float residual = fmaxf(1.0f - capsum, 0.0f);
        float redis[7], rs = 0.f;
        for (int i = 0; i < 7; ++i) {
            float fs = (fmass > 1e-6f) ? imp[i] * fr[i] / fmaxf(fmass, 1e-6f)
                                       : fr[i] * 0.2f;
            redis[i] = capped[i] + fs * residual;
            rs += redis[i];
        }
        float invr = 1.0f / fmaxf(rs, 1e-6f);
        for (int i = 0; i < 7; ++i) {
            float wi = redis[i] * invr;
            w[i] = wi;
            imp_out[b * 7 + i] = wi;
        }
    }
    __syncthreads();
    float wr[7];
    #pragma unroll
    for (int i = 0; i < 7; ++i) wr[i] = w[i];
    #pragma unroll
    for (int j = 0; j < 4; ++j) {
        int d = tid + j * 256;
        float s = 0.f;
        #pragma unroll
        for (int nn2 = 0; nn2 < 7; ++nn2)
            s += wr[nn2] * upd[(size_t)(b * 7 + nn2) * 1024 + d];
        fused_out[(size_t)b * 1024 + d] = s;
    }
}

__global__ void zero_acc(float* a) { if (threadIdx.x < 4) a[threadIdx.x] = 0.f; }

__global__ __launch_bounds__(256) void physics_k(
    const float* __restrict__ upd, const float* __restrict__ fused,
    float* __restrict__ accums)
{
    const int b = blockIdx.x;
    const int tid = threadIdx.x;
    const int lane = tid & 63, wv = tid >> 6;
    __shared__ float u[7][1024];
    __shared__ float f[1024];
    __shared__ float wred[4][36];
    for (int idx = tid; idx < 7 * 1024; idx += 256)
        u[idx >> 10][idx & 1023] = upd[(size_t)b * 7168 + idx];
    for (int d = tid; d < 1024; d += 256)
        f[d] = fused[(size_t)b * 1024 + d];
    __syncthreads();

    float vals[36];
    #pragma unroll
    for (int i = 0; i < 36; ++i) vals[i] = 0.f;
    for (int d = tid; d < 1024; d += 256) {
        float x[7];
        #pragma unroll
        for (int n = 0; n < 7; ++n) x[n] = u[n][d];
        float fv = f[d];
        int idx = 0;
        #pragma unroll
        for (int n = 0; n < 7; ++n) {
            #pragma unroll
            for (int m = n; m < 7; ++m) vals[idx++] += x[n] * x[m];
        }
        #pragma unroll
        for (int n = 0; n < 7; ++n) vals[28 + n] += x[n] * fv;
        vals[35] += fv * fv;
    }
    #pragma unroll
    for (int i = 0; i < 36; ++i) {
        float s = vals[i];
        #pragma unroll
        for (int off = 32; off > 0; off >>= 1) s += __shfl_down(s, off);
        if (lane == 0) wred[wv][i] = s;
    }
    __syncthreads();
    if (tid == 0) {
        float tv[36];
        for (int i = 0; i < 36; ++i)
            tv[i] = wred[0][i] + wred[1][i] + wred[2][i] + wred[3][i];
        auto didx = [](int n, int m) -> int {
            if (n > m) { int t = n; n = m; m = t; }
            return n * 7 - n * (n - 1) / 2 + (m - n);
        };
        float norms[7];
        for (int n = 0; n < 7; ++n) norms[n] = sqrtf(tv[didx(n, n)]);
        float e = 0.f, nl = 0.f;
        for (int n = 0; n < 7; ++n)
            for (int m = 0; m < 7; ++m) {
                float cos_ = tv[didx(n, m)] / fmaxf(norms[n] * norms[m], 1e-8f);
                float adj = c_adj[n * 7 + m];
                e += (1.0f - cos_) * adj;
                if (adj == 0.0f && n != m) nl += fmaxf(cos_ - 0.35f, 0.0f);
            }
        float fnorm = sqrtf(tv[35]);
        float al = 0.f;
        for (int n = 0; n < 7; ++n) {
            float cosn = tv[28 + n] /
                         (fmaxf(norms[n], 1e-12f) * fmaxf(fnorm, 1e-12f));
            al += 1.0f - cosn;
        }
        atomicAdd(&accums[0], e);
        atomicAdd(&accums[1], nl);
        atomicAdd(&accums[2], al);
    }
}

__global__ void finalize_k(const float* __restrict__ a,
                           float* __restrict__ phys_o,
                           float* __restrict__ align_o)
{
    phys_o[0]  = a[0] / 41.0f + 0.5f * (a[1] / 8.0f);
    align_o[0] = a[2] * (1.0f / 7168.0f);
}

extern "C" void kernel_launch(void* const* d_in, const int* in_sizes, int n_in,
                              void* d_out, int out_size, void* d_ws, size_t ws_size,
                              hipStream_t stream)
{
    const float* nodes = (const float*)d_in[0];
    const float* Wq  = (const float*)d_in[1];
    const float* bq  = (const float*)d_in[2];
    const float* Wk  = (const float*)d_in[3];
    const float* bk  = (const float*)d_in[4];
    const float* Wv  = (const float*)d_in[5];
    const float* bv  = (const float*)d_in[6];
    const float* We1 = (const float*)d_in[7];
    const float* be1 = (const float*)d_in[8];
    const float* We2 = (const float*)d_in[9];
    const float* be2 = (const float*)d_in[10];
    const float* Wu1 = (const float*)d_in[11];
    const float* bu1 = (const float*)d_in[12];
    const float* Wu2 = (const float*)d_in[13];
    const float* bu2 = (const float*)d_in[14];
    const float* Wi1 = (const float*)d_in[15];
    const float* bi1 = (const float*)d_in[16];
    const float* Wi2 = (const float*)d_in[17];
    const float* bi2 = (const float*)d_in[18];

    float* out = (float*)d_out;
    float* fused_o = out;                            // 1,048,576
    float* upd_o   = out + 1048576;                  // 7,340,032
    float* imp_o   = out + 1048576 + 7340032;        // 7,168
    float* attn_o  = imp_o + 7168;                   // 50,176
    float* phys_o  = attn_o + 50176;                 // 1
    float* align_o = phys_o + 1;                     // 1

    const size_t BIG = 7340032;   // B*N*D
    const size_t MEG = 1048576;   // D*D
    char* p = (char*)d_ws;
    unsigned short* nodes_b = (unsigned short*)p; p += BIG * 2;   // packed
    unsigned short* qb      = (unsigned short*)p; p += BIG * 2;   // rm seg 0; reused: h_u (packed)
    unsigned short* kb      = (unsigned short*)p; p += BIG * 2;   // rm seg 1; reused: upd_b (packed)
    unsigned short* vb      = (unsigned short*)p; p += BIG * 2;   // rm seg 2; reused: h_i (rm)
    unsigned short* lab     = (unsigned short*)p; p += BIG * 2;   // rm seg 3; reused: msg (rm)
    unsigned short* rbb     = (unsigned short*)p; p += BIG * 2;   // rm seg 4
    unsigned short* WT_all  = (unsigned short*)p; p += (size_t)6144 * 1024 * 2;  // packed
    unsigned short* Wu1T    = (unsigned short*)p; p += 2 * MEG * 2;  // packed
    unsigned short* Wu2T    = (unsigned short*)p; p += MEG * 2;      // packed
    unsigned short* Wi1T    = (unsigned short*)p; p += 2 * MEG * 2;  // packed
    float* bias_all = (float*)p; p += 5120 * 4;
    float* ccf = (float*)p; p += MEG * 4;
    float* il  = (float*)p; p += 7168 * 4;
    float* acc = (float*)p; p += 4 * 4;
    unsigned short* msgb = lab;   // alias: safe (see attn_msg_b)
    unsigned short* hub  = qb;
    unsigned short* updb = kb;
    unsigned short* hib  = vb;

    dim3 blk(256);

    // prep
    cast_f2b<<<dim3(7168), blk, 0, stream>>>(nodes, nodes_b, 7340032);
    tcast_all<<<dim3(32, 64, 9), blk, 0, stream>>>(Wq, Wk, Wv, We1, Wu1, Wu2, Wi1,
                                                   WT_all, Wu1T, Wu2T, Wi1T);
    build_bias<<<dim3(20), blk, 0, stream>>>(bq, bk, bv, bias_all);

    // fused q|k|v|la|rb : N=5120, row-major segmented bf16 out into qb..rbb
    gemm128<<<dim3(40, 56), blk, 0, stream>>>(
        nodes_b, 0, nullptr, 0, WT_all, 32, bias_all, nullptr,
        nullptr, qb, BIG, 1024, 0);

    // cc = nodes[:,-1] @ Wc + be1 (fp32 row-major out), WcT = WT_all seg 5
    gemm64x128<<<dim3(8, 16), blk, 0, stream>>>(
        nodes_b, 1, nullptr, 0, WT_all + (size_t)5 * MEG, 32, be1, nullptr,
        ccf, nullptr, 0, 1024, 0);

    // attention + messages (row-major; msg overwrites la)
    attn_msg_b<<<dim3(7168), blk, 0, stream>>>(qb, kb, vb, lab, rbb, ccf, We2, be2,
                                               attn_o, msgb);

    // h_u = gelu([nodes(packed)|msg(row-major)] @ Wu1 + bu1) -> packed
    gemm64x128<<<dim3(8, 112), blk, 0, stream>>>(
        nodes_b, 0, msgb, 3, Wu1T, 64, bu1, nullptr, nullptr, hub, 1, 2048, 1);
    // updated = h_u @ Wu2 + bu2 + nodes (fp32 out + packed bf16 copy)
    gemm64x128<<<dim3(8, 112), blk, 0, stream>>>(
        hub, 0, nullptr, 0, Wu2T, 32, bu2, nodes, upd_o, updb, 1, 1024, 0);
    // h_i = gelu([updated(packed)|ctx(packed)] @ Wi1 + bi1) -> row-major
    gemm64x128<<<dim3(8, 112), blk, 0, stream>>>(
        updb, 0, updb, 2, Wi1T, 64, bi1, nullptr, nullptr, hib, 0, 2048, 1);

    // tail
    row_dot_b<<<dim3(7168), blk, 0, stream>>>(hib, Wi2, bi2, il);
    imp_fused_k<<<dim3(1024), blk, 0, stream>>>(il, upd_o, imp_o, fused_o);
    zero_acc<<<1, 64, 0, stream>>>(acc);
    physics_k<<<dim3(1024), blk, 0, stream>>>(upd_o, fused_o, acc);
    finalize_k<<<1, 1, 0, stream>>>(acc, phys_o, align_o);
}